// Round 1
// baseline (529.626 us; speedup 1.0000x reference)
//
#include <hip/hip_runtime.h>
#include <math.h>

#define HFD 128
#define WFD 128
#define DFD 512
#define KA  4
#define NA  (HFD*WFD*KA)      // 65536
#define MAXD 512
#define HID 1024
#define FIN 4608              // 3*3*512
#define NB  1025
#define CMAX 2048
#define TAUF 0.5f
#define NMS_THR 0.3f

// ---------------------------------------------------------------- init
__global__ void init_kernel(unsigned* hist, unsigned* cnt) {
    int t = blockIdx.x * blockDim.x + threadIdx.x;
    if (t < NB) hist[t] = 0u;
    if (t == 0) cnt[0] = 0u;
}

// ------------------------------------------------- score + box decode
__global__ void score_box_kernel(const float* __restrict__ rpn_obj,
                                 const float* __restrict__ rpn_reg,
                                 const float* __restrict__ anchors,
                                 float* __restrict__ scores,
                                 float* __restrict__ boxes,
                                 unsigned* __restrict__ hist) {
    int n = blockIdx.x * blockDim.x + threadIdx.x;
    if (n >= NA) return;
    int k = n & 3;
    int cell = n >> 2;              // i*WF + j
    float o0 = rpn_obj[cell * 8 + 2 * k];
    float o1 = rpn_obj[cell * 8 + 2 * k + 1];
    float m  = fmaxf(o0, o1);
    float e0 = expf(o0 - m), e1 = expf(o1 - m);
    float s  = e1 / (e0 + e1);

    float r0 = rpn_reg[cell * 16 + 4 * k + 0];
    float r1 = rpn_reg[cell * 16 + 4 * k + 1];
    float r2 = rpn_reg[cell * 16 + 4 * k + 2];
    float r3 = rpn_reg[cell * 16 + 4 * k + 3];

    float ax = anchors[n * 4 + 0];
    float ay = anchors[n * 4 + 1];
    float aw = anchors[n * 4 + 2];
    float ah = anchors[n * 4 + 3];

    float acx = ax + aw * 0.5f;
    float acy = ay + ah * 0.5f;
    float cx = acx + r0 * aw;
    float cy = acy + r1 * ah;
    float w  = aw * expf(r2);
    float h  = ah * expf(r3);

    boxes[n * 4 + 0] = cx - 0.5f * w;
    boxes[n * 4 + 1] = cy - 0.5f * h;
    boxes[n * 4 + 2] = w;
    boxes[n * 4 + 3] = h;

    scores[n] = (s > TAUF) ? s : -INFINITY;
    if (s > TAUF) {
        unsigned bits = __float_as_uint(s);
        unsigned b = (bits - 0x3F000000u) >> 13;   // 0..1024
        atomicAdd(&hist[b], 1u);
    }
}

// ------------------------------------------- find threshold bucket
__global__ void bucket_threshold_kernel(const unsigned* __restrict__ hist,
                                        unsigned* __restrict__ thr) {
    __shared__ unsigned h[NB];
    for (int i = threadIdx.x; i < NB; i += blockDim.x) h[i] = hist[i];
    __syncthreads();
    if (threadIdx.x == 0) {
        unsigned acc = 0;
        int b = NB - 1;
        for (; b >= 0; --b) {
            acc += h[b];
            if (acc >= MAXD) break;
        }
        if (b < 0) b = 0;
        thr[0] = (unsigned)b;
    }
}

// ------------------------------------------------------- compaction
__global__ void compact_kernel(const float* __restrict__ scores,
                               const unsigned* __restrict__ thr,
                               unsigned* __restrict__ cnt,
                               unsigned long long* __restrict__ cand) {
    int n = blockIdx.x * blockDim.x + threadIdx.x;
    if (n >= NA) return;
    float s = scores[n];
    if (s > TAUF) {
        unsigned bits = __float_as_uint(s);
        unsigned b = (bits - 0x3F000000u) >> 13;
        if (b >= thr[0]) {
            unsigned pos = atomicAdd(cnt, 1u);
            if (pos < CMAX) {
                cand[pos] = ((unsigned long long)bits << 32) |
                            (unsigned long long)(~(unsigned)n);
            }
        }
    }
}

// --------------------------------- single-block bitonic sort + top-512
__global__ __launch_bounds__(1024)
void sort_topk_kernel(const unsigned long long* __restrict__ cand,
                      const unsigned* __restrict__ cnt_p,
                      const float* __restrict__ boxes,
                      unsigned* __restrict__ top_idx,
                      float* __restrict__ top_score,
                      unsigned* __restrict__ valid,
                      float* __restrict__ sel) {
    __shared__ unsigned long long keys[CMAX];
    unsigned cnt = *cnt_p;
    if (cnt > CMAX) cnt = CMAX;
    for (int i = threadIdx.x; i < CMAX; i += blockDim.x)
        keys[i] = (i < (int)cnt) ? cand[i] : 0ULL;
    __syncthreads();

    for (int k = 2; k <= CMAX; k <<= 1) {
        for (int j = k >> 1; j > 0; j >>= 1) {
            for (int i = threadIdx.x; i < CMAX; i += blockDim.x) {
                int ixj = i ^ j;
                if (ixj > i) {
                    unsigned long long a = keys[i], b = keys[ixj];
                    bool up = ((i & k) == 0);       // descending overall
                    if ((a < b) == up) { keys[i] = b; keys[ixj] = a; }
                }
            }
            __syncthreads();
        }
    }

    for (int r = threadIdx.x; r < MAXD; r += blockDim.x) {
        unsigned long long e = keys[r];
        unsigned sbits = (unsigned)(e >> 32);
        bool v = (sbits != 0u);
        unsigned idx = v ? (unsigned)(~(unsigned)e) : 0u;
        top_idx[r]   = idx;
        top_score[r] = v ? __uint_as_float(sbits) : 0.0f;
        valid[r]     = v ? 1u : 0u;
        float4 b = *(const float4*)&boxes[idx * 4];
        ((float4*)sel)[r] = b;
    }
}

// ---------------------------------------------------- IoU bitmask
__global__ __launch_bounds__(512)
void iou_mask_kernel(const float* __restrict__ sel,
                     unsigned long long* __restrict__ mask) {
    int i = blockIdx.x;
    int j = threadIdx.x;
    float4 bi = ((const float4*)sel)[i];
    float4 bj = ((const float4*)sel)[j];
    float x1i = bi.x, y1i = bi.y, x2i = bi.x + bi.z, y2i = bi.y + bi.w;
    float x1j = bj.x, y1j = bj.y, x2j = bj.x + bj.z, y2j = bj.y + bj.w;
    float ai = bi.z * bi.w, aj = bj.z * bj.w;
    float ix = fmaxf(0.0f, fminf(x2i, x2j) - fmaxf(x1i, x1j));
    float iy = fmaxf(0.0f, fminf(y2i, y2j) - fmaxf(y1i, y1j));
    float inter = ix * iy;
    float iou = inter / (ai + aj - inter + 1e-8f);
    unsigned long long bal = __ballot(iou > NMS_THR);
    if ((j & 63) == 0) mask[i * 8 + (j >> 6)] = bal;
}

// -------------------------------------------- sequential NMS (1 wave)
__global__ __launch_bounds__(64)
void nms_scan_kernel(const unsigned long long* __restrict__ mask,
                     const unsigned* __restrict__ valid,
                     unsigned* __restrict__ keep) {
    __shared__ unsigned long long m[MAXD * 8];
    __shared__ unsigned v[MAXD];
    __shared__ unsigned kp[MAXD];
    int lane = threadIdx.x;
    for (int i = lane; i < MAXD * 8; i += 64) m[i] = mask[i];
    for (int i = lane; i < MAXD; i += 64) v[i] = valid[i];
    __syncthreads();
    unsigned long long keepw = 0ULL;
    for (int i = 0; i < MAXD; ++i) {
        unsigned long long row = (lane < 8) ? m[i * 8 + lane] : 0ULL;
        bool hit = __any((row & keepw) != 0ULL);
        bool k = (v[i] != 0u) && !hit;
        if (lane == (i >> 6))
            keepw |= ((unsigned long long)(k ? 1 : 0)) << (i & 63);
        if (lane == 0) kp[i] = k ? 1u : 0u;
    }
    __syncthreads();
    for (int i = lane; i < MAXD; i += 64) keep[i] = kp[i];
}

// ------------------------------------------------------- ROI align
__global__ __launch_bounds__(256)
void roialign_kernel(const float* __restrict__ feat,
                     const float* __restrict__ sel,
                     float* __restrict__ pooled) {
    int mrow = blockIdx.x;
    int c = threadIdx.x;           // channels c and c+256
    float4 b = ((const float4*)sel)[mrow];
    float bx = b.x, by = b.y, bw = b.z, bh = b.w;
    float vmax0[9], vmax1[9];
#pragma unroll
    for (int t = 0; t < 9; ++t) { vmax0[t] = -INFINITY; vmax1[t] = -INFINITY; }
#pragma unroll
    for (int p = 0; p < 6; ++p) {
        float fy = (by + ((float)p + 0.5f) / 6.0f * bh) / 16.0f - 0.5f;
        fy = fminf(fmaxf(fy, 0.0f), 127.0f);
        int y0 = (int)floorf(fy);
        int y1 = min(y0 + 1, 127);
        float wy = fy - (float)y0;
#pragma unroll
        for (int q = 0; q < 6; ++q) {
            float fx = (bx + ((float)q + 0.5f) / 6.0f * bw) / 16.0f - 0.5f;
            fx = fminf(fmaxf(fx, 0.0f), 127.0f);
            int x0 = (int)floorf(fx);
            int x1 = min(x0 + 1, 127);
            float wx = fx - (float)x0;
            const float* f00 = feat + (y0 * WFD + x0) * DFD;
            const float* f01 = feat + (y0 * WFD + x1) * DFD;
            const float* f10 = feat + (y1 * WFD + x0) * DFD;
            const float* f11 = feat + (y1 * WFD + x1) * DFD;
            float w00 = (1.0f - wy) * (1.0f - wx);
            float w01 = (1.0f - wy) * wx;
            float w10 = wy * (1.0f - wx);
            float w11 = wy * wx;
            int t = (p >> 1) * 3 + (q >> 1);
            float v0 = f00[c] * w00 + f01[c] * w01 + f10[c] * w10 + f11[c] * w11;
            float v1 = f00[c + 256] * w00 + f01[c + 256] * w01 +
                       f10[c + 256] * w10 + f11[c + 256] * w11;
            vmax0[t] = fmaxf(vmax0[t], v0);
            vmax1[t] = fmaxf(vmax1[t], v1);
        }
    }
#pragma unroll
    for (int t = 0; t < 9; ++t) {
        pooled[mrow * FIN + t * DFD + c] = vmax0[t];
        pooled[mrow * FIN + t * DFD + c + 256] = vmax1[t];
    }
}

// --------------------------------------------- fp32 tiled GEMM + relu
// C[M x N] = relu(A[M x K] * B[K x N] + bias), M=512, N=1024
__global__ __launch_bounds__(256)
void gemm_relu_kernel(const float* __restrict__ A,
                      const float* __restrict__ B,
                      const float* __restrict__ bias,
                      float* __restrict__ C,
                      int K, int N) {
    __shared__ float As[16 * 68];
    __shared__ float Bs[16 * 68];
    int tid = threadIdx.x;
    int tx = tid & 15, ty = tid >> 4;
    int bm = blockIdx.y * 64, bn = blockIdx.x * 64;

    float acc[4][4] = {};
    int arow = tid >> 2, akc = (tid & 3) << 2;
    int brow = tid >> 4, bnc = (tid & 15) << 2;
    const float* Aptr = A + (bm + arow) * K + akc;
    const float* Bptr = B + brow * N + bn + bnc;

    for (int k0 = 0; k0 < K; k0 += 16) {
        float4 a4 = *(const float4*)(Aptr + k0);
        float4 b4 = *(const float4*)(Bptr + (long)k0 * N);
        As[(akc + 0) * 68 + arow] = a4.x;
        As[(akc + 1) * 68 + arow] = a4.y;
        As[(akc + 2) * 68 + arow] = a4.z;
        As[(akc + 3) * 68 + arow] = a4.w;
        *(float4*)&Bs[brow * 68 + bnc] = b4;
        __syncthreads();
#pragma unroll
        for (int kk = 0; kk < 16; ++kk) {
            float4 av = *(const float4*)&As[kk * 68 + ty * 4];
            float4 bv = *(const float4*)&Bs[kk * 68 + tx * 4];
            float a[4] = {av.x, av.y, av.z, av.w};
            float bb[4] = {bv.x, bv.y, bv.z, bv.w};
#pragma unroll
            for (int i = 0; i < 4; ++i)
#pragma unroll
                for (int j = 0; j < 4; ++j)
                    acc[i][j] += a[i] * bb[j];
        }
        __syncthreads();
    }

#pragma unroll
    for (int i = 0; i < 4; ++i) {
        int row = bm + ty * 4 + i;
        int col = bn + tx * 4;
        float4 o;
        o.x = fmaxf(acc[i][0] + bias[col + 0], 0.0f);
        o.y = fmaxf(acc[i][1] + bias[col + 1], 0.0f);
        o.z = fmaxf(acc[i][2] + bias[col + 2], 0.0f);
        o.w = fmaxf(acc[i][3] + bias[col + 3], 0.0f);
        *(float4*)&C[(long)row * N + col] = o;
    }
}

// ------------------------------ final tiny GEMM (N=4) + refine epilogue
__global__ __launch_bounds__(64)
void head_kernel(const float* __restrict__ h2,
                 const float* __restrict__ W3,
                 const float* __restrict__ b3,
                 const float* __restrict__ sel,
                 const float* __restrict__ top_score,
                 const unsigned* __restrict__ valid,
                 const unsigned* __restrict__ keep,
                 float* __restrict__ out) {
    int r = blockIdx.x;
    int lane = threadIdx.x;
    float a0 = 0.f, a1 = 0.f, a2 = 0.f, a3 = 0.f;
    for (int k = lane; k < HID; k += 64) {
        float hv = h2[r * HID + k];
        float4 w = *(const float4*)&W3[k * 4];
        a0 += hv * w.x;
        a1 += hv * w.y;
        a2 += hv * w.z;
        a3 += hv * w.w;
    }
#pragma unroll
    for (int off = 32; off > 0; off >>= 1) {
        a0 += __shfl_down(a0, off);
        a1 += __shfl_down(a1, off);
        a2 += __shfl_down(a2, off);
        a3 += __shfl_down(a3, off);
    }
    if (lane == 0) {
        if (keep[r] != 0u) {
            float d0 = a0 + b3[0], d1 = a1 + b3[1];
            float d2 = a2 + b3[2], d3 = a3 + b3[3];
            float4 b = ((const float4*)sel)[r];
            float acx = b.x + 0.5f * b.z;
            float acy = b.y + 0.5f * b.w;
            float cx = acx + d0 * b.z;
            float cy = acy + d1 * b.w;
            float nw = b.z * expf(d2);
            float nh = b.w * expf(d3);
            out[r * 5 + 0] = cx - 0.5f * nw;
            out[r * 5 + 1] = cy - 0.5f * nh;
            out[r * 5 + 2] = nw;
            out[r * 5 + 3] = nh;
            out[r * 5 + 4] = (valid[r] != 0u) ? top_score[r] : 0.0f;
        } else {
            out[r * 5 + 0] = 0.0f;
            out[r * 5 + 1] = 0.0f;
            out[r * 5 + 2] = 0.0f;
            out[r * 5 + 3] = 0.0f;
            out[r * 5 + 4] = 0.0f;
        }
    }
}

// ---------------------------------------------------------------- host
extern "C" void kernel_launch(void* const* d_in, const int* in_sizes, int n_in,
                              void* d_out, int out_size, void* d_ws, size_t ws_size,
                              hipStream_t stream) {
    const float* features = (const float*)d_in[0];
    const float* rpn_obj  = (const float*)d_in[1];
    const float* rpn_reg  = (const float*)d_in[2];
    const float* anchors  = (const float*)d_in[3];
    const float* W1 = (const float*)d_in[4];
    const float* b1 = (const float*)d_in[5];
    const float* W2 = (const float*)d_in[6];
    const float* b2 = (const float*)d_in[7];
    const float* W3 = (const float*)d_in[8];
    const float* b3 = (const float*)d_in[9];
    float* out = (float*)d_out;

    char* ws = (char*)d_ws;
    size_t off = 0;
    auto alloc = [&](size_t bytes) {
        char* p = ws + off;
        off += (bytes + 255) & ~(size_t)255;
        return p;
    };
    float*    scores    = (float*)alloc(NA * sizeof(float));
    float*    boxes     = (float*)alloc(NA * 4 * sizeof(float));
    unsigned* hist      = (unsigned*)alloc(NB * sizeof(unsigned));
    unsigned* thr       = (unsigned*)alloc(sizeof(unsigned));
    unsigned* cnt       = (unsigned*)alloc(sizeof(unsigned));
    unsigned long long* cand = (unsigned long long*)alloc(CMAX * 8);
    unsigned* top_idx   = (unsigned*)alloc(MAXD * sizeof(unsigned));
    float*    top_score = (float*)alloc(MAXD * sizeof(float));
    unsigned* valid     = (unsigned*)alloc(MAXD * sizeof(unsigned));
    float*    sel       = (float*)alloc(MAXD * 4 * sizeof(float));
    unsigned long long* mask = (unsigned long long*)alloc(MAXD * 8 * 8);
    unsigned* keep      = (unsigned*)alloc(MAXD * sizeof(unsigned));
    float*    pooled    = (float*)alloc((size_t)MAXD * FIN * sizeof(float));
    float*    h1        = (float*)alloc((size_t)MAXD * HID * sizeof(float));
    float*    h2        = (float*)alloc((size_t)MAXD * HID * sizeof(float));
    (void)ws_size; (void)in_sizes; (void)n_in; (void)out_size;

    init_kernel<<<(NB + 255) / 256, 256, 0, stream>>>(hist, cnt);
    score_box_kernel<<<NA / 256, 256, 0, stream>>>(rpn_obj, rpn_reg, anchors,
                                                   scores, boxes, hist);
    bucket_threshold_kernel<<<1, 1024, 0, stream>>>(hist, thr);
    compact_kernel<<<NA / 256, 256, 0, stream>>>(scores, thr, cnt, cand);
    sort_topk_kernel<<<1, 1024, 0, stream>>>(cand, cnt, boxes,
                                             top_idx, top_score, valid, sel);
    iou_mask_kernel<<<MAXD, 512, 0, stream>>>(sel, mask);
    nms_scan_kernel<<<1, 64, 0, stream>>>(mask, valid, keep);
    roialign_kernel<<<MAXD, 256, 0, stream>>>(features, sel, pooled);

    dim3 g1(HID / 64, MAXD / 64);
    gemm_relu_kernel<<<g1, 256, 0, stream>>>(pooled, W1, b1, h1, FIN, HID);
    gemm_relu_kernel<<<g1, 256, 0, stream>>>(h1, W2, b2, h2, HID, HID);
    head_kernel<<<MAXD, 64, 0, stream>>>(h2, W3, b3, sel, top_score, valid,
                                         keep, out);
}

// Round 2
// 275.344 us; speedup vs baseline: 1.9235x; 1.9235x over previous
//
#include <hip/hip_runtime.h>
#include <math.h>

#define HFD 128
#define WFD 128
#define DFD 512
#define KA  4
#define NA  (HFD*WFD*KA)      // 65536
#define MAXD 512
#define HID 1024
#define FIN 4608              // 3*3*512
#define NB  1025
#define CMAX 2048
#define TAUF 0.5f
#define NMS_THR 0.3f
#define SPLITK 8

typedef __bf16 bf16x8 __attribute__((ext_vector_type(8)));
typedef float  floatx4 __attribute__((ext_vector_type(4)));

__device__ __forceinline__ unsigned short f2bf(float x) {
    unsigned u = __float_as_uint(x);
    unsigned r = (u + 0x7FFFu + ((u >> 16) & 1u)) >> 16;   // RNE
    return (unsigned short)r;
}

// ---------------------------------------------------------------- init
__global__ void init_kernel(unsigned* hist, unsigned* cnt) {
    int t = blockIdx.x * blockDim.x + threadIdx.x;
    if (t < NB) hist[t] = 0u;
    if (t == 0) cnt[0] = 0u;
}

// ------------------------------------------------- score + box decode
__global__ void score_box_kernel(const float* __restrict__ rpn_obj,
                                 const float* __restrict__ rpn_reg,
                                 const float* __restrict__ anchors,
                                 float* __restrict__ scores,
                                 float* __restrict__ boxes,
                                 unsigned* __restrict__ hist) {
    int n = blockIdx.x * blockDim.x + threadIdx.x;
    if (n >= NA) return;
    int k = n & 3;
    int cell = n >> 2;
    float o0 = rpn_obj[cell * 8 + 2 * k];
    float o1 = rpn_obj[cell * 8 + 2 * k + 1];
    float m  = fmaxf(o0, o1);
    float e0 = expf(o0 - m), e1 = expf(o1 - m);
    float s  = e1 / (e0 + e1);

    float r0 = rpn_reg[cell * 16 + 4 * k + 0];
    float r1 = rpn_reg[cell * 16 + 4 * k + 1];
    float r2 = rpn_reg[cell * 16 + 4 * k + 2];
    float r3 = rpn_reg[cell * 16 + 4 * k + 3];

    float ax = anchors[n * 4 + 0];
    float ay = anchors[n * 4 + 1];
    float aw = anchors[n * 4 + 2];
    float ah = anchors[n * 4 + 3];

    float acx = ax + aw * 0.5f;
    float acy = ay + ah * 0.5f;
    float cx = acx + r0 * aw;
    float cy = acy + r1 * ah;
    float w  = aw * expf(r2);
    float h  = ah * expf(r3);

    boxes[n * 4 + 0] = cx - 0.5f * w;
    boxes[n * 4 + 1] = cy - 0.5f * h;
    boxes[n * 4 + 2] = w;
    boxes[n * 4 + 3] = h;

    scores[n] = (s > TAUF) ? s : -INFINITY;
    if (s > TAUF) {
        unsigned bits = __float_as_uint(s);
        unsigned b = (bits - 0x3F000000u) >> 13;   // 0..1024
        atomicAdd(&hist[b], 1u);
    }
}

// ------------------------------------------- find threshold bucket
__global__ void bucket_threshold_kernel(const unsigned* __restrict__ hist,
                                        unsigned* __restrict__ thr) {
    __shared__ unsigned h[NB];
    for (int i = threadIdx.x; i < NB; i += blockDim.x) h[i] = hist[i];
    __syncthreads();
    if (threadIdx.x == 0) {
        unsigned acc = 0;
        int b = NB - 1;
        for (; b >= 0; --b) {
            acc += h[b];
            if (acc >= MAXD) break;
        }
        if (b < 0) b = 0;
        thr[0] = (unsigned)b;
    }
}

// ------------------------------------------------------- compaction
__global__ void compact_kernel(const float* __restrict__ scores,
                               const unsigned* __restrict__ thr,
                               unsigned* __restrict__ cnt,
                               unsigned long long* __restrict__ cand) {
    int n = blockIdx.x * blockDim.x + threadIdx.x;
    if (n >= NA) return;
    float s = scores[n];
    if (s > TAUF) {
        unsigned bits = __float_as_uint(s);
        unsigned b = (bits - 0x3F000000u) >> 13;
        if (b >= thr[0]) {
            unsigned pos = atomicAdd(cnt, 1u);
            if (pos < CMAX) {
                cand[pos] = ((unsigned long long)bits << 32) |
                            (unsigned long long)(~(unsigned)n);
            }
        }
    }
}

// --------------------------------- single-block bitonic sort + top-512
__global__ __launch_bounds__(1024)
void sort_topk_kernel(const unsigned long long* __restrict__ cand,
                      const unsigned* __restrict__ cnt_p,
                      const float* __restrict__ boxes,
                      unsigned* __restrict__ top_idx,
                      float* __restrict__ top_score,
                      unsigned* __restrict__ valid,
                      float* __restrict__ sel) {
    __shared__ unsigned long long keys[CMAX];
    unsigned cnt = *cnt_p;
    if (cnt > CMAX) cnt = CMAX;
    for (int i = threadIdx.x; i < CMAX; i += blockDim.x)
        keys[i] = (i < (int)cnt) ? cand[i] : 0ULL;
    __syncthreads();

    for (int k = 2; k <= CMAX; k <<= 1) {
        for (int j = k >> 1; j > 0; j >>= 1) {
            for (int i = threadIdx.x; i < CMAX; i += blockDim.x) {
                int ixj = i ^ j;
                if (ixj > i) {
                    unsigned long long a = keys[i], b = keys[ixj];
                    bool up = ((i & k) == 0);       // descending overall
                    if ((a < b) == up) { keys[i] = b; keys[ixj] = a; }
                }
            }
            __syncthreads();
        }
    }

    for (int r = threadIdx.x; r < MAXD; r += blockDim.x) {
        unsigned long long e = keys[r];
        unsigned sbits = (unsigned)(e >> 32);
        bool v = (sbits != 0u);
        unsigned idx = v ? (unsigned)(~(unsigned)e) : 0u;
        top_idx[r]   = idx;
        top_score[r] = v ? __uint_as_float(sbits) : 0.0f;
        valid[r]     = v ? 1u : 0u;
        float4 b = *(const float4*)&boxes[idx * 4];
        ((float4*)sel)[r] = b;
    }
}

// ---------------------------------------------------- IoU bitmask
__global__ __launch_bounds__(512)
void iou_mask_kernel(const float* __restrict__ sel,
                     unsigned long long* __restrict__ mask) {
    int i = blockIdx.x;
    int j = threadIdx.x;
    float4 bi = ((const float4*)sel)[i];
    float4 bj = ((const float4*)sel)[j];
    float x2i = bi.x + bi.z, y2i = bi.y + bi.w;
    float x2j = bj.x + bj.z, y2j = bj.y + bj.w;
    float ai = bi.z * bi.w, aj = bj.z * bj.w;
    float ix = fmaxf(0.0f, fminf(x2i, x2j) - fmaxf(bi.x, bj.x));
    float iy = fmaxf(0.0f, fminf(y2i, y2j) - fmaxf(bi.y, bj.y));
    float inter = ix * iy;
    float iou = inter / (ai + aj - inter + 1e-8f);
    unsigned long long bal = __ballot(iou > NMS_THR);
    if ((j & 63) == 0) mask[i * 8 + (j >> 6)] = bal;
}

// -------------------------------------------- sequential NMS (1 wave)
__global__ __launch_bounds__(64)
void nms_scan_kernel(const unsigned long long* __restrict__ mask,
                     const unsigned* __restrict__ valid,
                     unsigned* __restrict__ keep) {
    __shared__ unsigned long long m[MAXD * 8];
    __shared__ unsigned v[MAXD];
    __shared__ unsigned kp[MAXD];
    int lane = threadIdx.x;
    for (int i = lane; i < MAXD * 8; i += 64) m[i] = mask[i];
    for (int i = lane; i < MAXD; i += 64) v[i] = valid[i];
    __syncthreads();
    unsigned long long keepw = 0ULL;
    for (int i = 0; i < MAXD; ++i) {
        unsigned long long row = (lane < 8) ? m[i * 8 + lane] : 0ULL;
        bool hit = __any((row & keepw) != 0ULL);
        bool k = (v[i] != 0u) && !hit;
        if (lane == (i >> 6))
            keepw |= ((unsigned long long)(k ? 1 : 0)) << (i & 63);
        if (lane == 0) kp[i] = k ? 1u : 0u;
    }
    __syncthreads();
    for (int i = lane; i < MAXD; i += 64) keep[i] = kp[i];
}

// ------------------------------------------- ROI align (bf16 output)
__global__ __launch_bounds__(256)
void roialign_kernel(const float* __restrict__ feat,
                     const float* __restrict__ sel,
                     unsigned short* __restrict__ pooled) {
    int mrow = blockIdx.x;
    int c = threadIdx.x;           // channels c and c+256
    float4 b = ((const float4*)sel)[mrow];
    float bx = b.x, by = b.y, bw = b.z, bh = b.w;
    float vmax0[9], vmax1[9];
#pragma unroll
    for (int t = 0; t < 9; ++t) { vmax0[t] = -INFINITY; vmax1[t] = -INFINITY; }
#pragma unroll
    for (int p = 0; p < 6; ++p) {
        float fy = (by + ((float)p + 0.5f) / 6.0f * bh) / 16.0f - 0.5f;
        fy = fminf(fmaxf(fy, 0.0f), 127.0f);
        int y0 = (int)floorf(fy);
        int y1 = min(y0 + 1, 127);
        float wy = fy - (float)y0;
#pragma unroll
        for (int q = 0; q < 6; ++q) {
            float fx = (bx + ((float)q + 0.5f) / 6.0f * bw) / 16.0f - 0.5f;
            fx = fminf(fmaxf(fx, 0.0f), 127.0f);
            int x0 = (int)floorf(fx);
            int x1 = min(x0 + 1, 127);
            float wx = fx - (float)x0;
            const float* f00 = feat + (y0 * WFD + x0) * DFD;
            const float* f01 = feat + (y0 * WFD + x1) * DFD;
            const float* f10 = feat + (y1 * WFD + x0) * DFD;
            const float* f11 = feat + (y1 * WFD + x1) * DFD;
            float w00 = (1.0f - wy) * (1.0f - wx);
            float w01 = (1.0f - wy) * wx;
            float w10 = wy * (1.0f - wx);
            float w11 = wy * wx;
            int t = (p >> 1) * 3 + (q >> 1);
            float v0 = f00[c] * w00 + f01[c] * w01 + f10[c] * w10 + f11[c] * w11;
            float v1 = f00[c + 256] * w00 + f01[c + 256] * w01 +
                       f10[c + 256] * w10 + f11[c + 256] * w11;
            vmax0[t] = fmaxf(vmax0[t], v0);
            vmax1[t] = fmaxf(vmax1[t], v1);
        }
    }
#pragma unroll
    for (int t = 0; t < 9; ++t) {
        pooled[mrow * FIN + t * DFD + c] = f2bf(vmax0[t]);
        pooled[mrow * FIN + t * DFD + c + 256] = f2bf(vmax1[t]);
    }
}

// ----------------------------- fp32 W[K][N] -> bf16 Wt[N][K] transpose
__global__ __launch_bounds__(256)
void transpose_bf16_kernel(const float* __restrict__ W,
                           unsigned short* __restrict__ Wt,
                           int K, int N) {
    __shared__ float tile[32][33];
    int bk = blockIdx.y * 32;
    int bn = blockIdx.x * 32;
    int tx = threadIdx.x & 31, ty = threadIdx.x >> 5;   // ty 0..7
#pragma unroll
    for (int r = 0; r < 32; r += 8)
        tile[ty + r][tx] = W[(long)(bk + ty + r) * N + bn + tx];
    __syncthreads();
#pragma unroll
    for (int r = 0; r < 32; r += 8)
        Wt[(long)(bn + ty + r) * K + bk + tx] = f2bf(tile[tx][ty + r]);
}

// --------------------------------------- bf16 MFMA GEMM with split-K
// A: M x K bf16 row-major; Bt: N x K bf16 row-major (B transposed)
// Cpart[z][M][N] fp32 partials. grid = (N/64, M/64, SPLITK), 256 thr.
#define LDSTRIDE 40
__global__ __launch_bounds__(256)
void mfma_gemm_kernel(const unsigned short* __restrict__ A,
                      const unsigned short* __restrict__ Bt,
                      float* __restrict__ Cpart,
                      int M, int N, int K) {
    __shared__ unsigned short As[64 * LDSTRIDE];
    __shared__ unsigned short Bs[64 * LDSTRIDE];
    int tid = threadIdx.x;
    int wave = tid >> 6, lane = tid & 63;
    int bm = blockIdx.y * 64, bn = blockIdx.x * 64;
    int KC = K / SPLITK;
    int ks = blockIdx.z * KC;

    floatx4 acc[4] = {};
    int lr = tid >> 2;            // 0..63  staging row
    int lk = (tid & 3) << 3;      // 0,8,16,24  staging k-offset
    int frow = lane & 15, quad = lane >> 4;

    const unsigned short* Ap = A + (long)(bm + lr) * K + lk;
    const unsigned short* Bp = Bt + (long)(bn + lr) * K + lk;

    for (int k0 = ks; k0 < ks + KC; k0 += 32) {
        uint4 av = *(const uint4*)(Ap + k0);
        uint4 bv = *(const uint4*)(Bp + k0);
        *(uint4*)&As[lr * LDSTRIDE + lk] = av;
        *(uint4*)&Bs[lr * LDSTRIDE + lk] = bv;
        __syncthreads();
        bf16x8 af = *(const bf16x8*)&As[(wave * 16 + frow) * LDSTRIDE + quad * 8];
#pragma unroll
        for (int t = 0; t < 4; ++t) {
            bf16x8 bfv = *(const bf16x8*)&Bs[(t * 16 + frow) * LDSTRIDE + quad * 8];
            acc[t] = __builtin_amdgcn_mfma_f32_16x16x32_bf16(af, bfv, acc[t], 0, 0, 0);
        }
        __syncthreads();
    }

    float* Cp = Cpart + (long)blockIdx.z * M * N;
#pragma unroll
    for (int t = 0; t < 4; ++t) {
#pragma unroll
        for (int r = 0; r < 4; ++r) {
            int m = bm + wave * 16 + quad * 4 + r;   // C row = quad*4+reg
            int n = bn + t * 16 + frow;              // C col = lane&15
            Cp[(long)m * N + n] = acc[t][r];
        }
    }
}

// --------------------- split-K reduce + bias + relu, bf16/fp32 output
__global__ __launch_bounds__(256)
void reduce_bias_relu_kernel(const float* __restrict__ Cpart,
                             const float* __restrict__ bias,
                             unsigned short* __restrict__ out_bf,
                             float* __restrict__ out_f,
                             int MN, int N) {
    int i4 = (blockIdx.x * blockDim.x + threadIdx.x) * 4;
    if (i4 >= MN) return;
    float4 s = *(const float4*)&Cpart[i4];
#pragma unroll
    for (int z = 1; z < SPLITK; ++z) {
        float4 p = *(const float4*)&Cpart[(long)z * MN + i4];
        s.x += p.x; s.y += p.y; s.z += p.z; s.w += p.w;
    }
    int n = i4 & (N - 1);
    float4 bi = *(const float4*)&bias[n];
    s.x = fmaxf(s.x + bi.x, 0.0f);
    s.y = fmaxf(s.y + bi.y, 0.0f);
    s.z = fmaxf(s.z + bi.z, 0.0f);
    s.w = fmaxf(s.w + bi.w, 0.0f);
    if (out_bf) {
        uint2 o;
        o.x = (unsigned)f2bf(s.x) | ((unsigned)f2bf(s.y) << 16);
        o.y = (unsigned)f2bf(s.z) | ((unsigned)f2bf(s.w) << 16);
        *(uint2*)&out_bf[i4] = o;
    }
    if (out_f) *(float4*)&out_f[i4] = s;
}

// ------------------------------ final tiny GEMM (N=4) + refine epilogue
__global__ __launch_bounds__(64)
void head_kernel(const float* __restrict__ h2,
                 const float* __restrict__ W3,
                 const float* __restrict__ b3,
                 const float* __restrict__ sel,
                 const float* __restrict__ top_score,
                 const unsigned* __restrict__ valid,
                 const unsigned* __restrict__ keep,
                 float* __restrict__ out) {
    int r = blockIdx.x;
    int lane = threadIdx.x;
    float a0 = 0.f, a1 = 0.f, a2 = 0.f, a3 = 0.f;
    for (int k = lane; k < HID; k += 64) {
        float hv = h2[r * HID + k];
        float4 w = *(const float4*)&W3[k * 4];
        a0 += hv * w.x;
        a1 += hv * w.y;
        a2 += hv * w.z;
        a3 += hv * w.w;
    }
#pragma unroll
    for (int off = 32; off > 0; off >>= 1) {
        a0 += __shfl_down(a0, off);
        a1 += __shfl_down(a1, off);
        a2 += __shfl_down(a2, off);
        a3 += __shfl_down(a3, off);
    }
    if (lane == 0) {
        if (keep[r] != 0u) {
            float d0 = a0 + b3[0], d1 = a1 + b3[1];
            float d2 = a2 + b3[2], d3 = a3 + b3[3];
            float4 b = ((const float4*)sel)[r];
            float acx = b.x + 0.5f * b.z;
            float acy = b.y + 0.5f * b.w;
            float cx = acx + d0 * b.z;
            float cy = acy + d1 * b.w;
            float nw = b.z * expf(d2);
            float nh = b.w * expf(d3);
            out[r * 5 + 0] = cx - 0.5f * nw;
            out[r * 5 + 1] = cy - 0.5f * nh;
            out[r * 5 + 2] = nw;
            out[r * 5 + 3] = nh;
            out[r * 5 + 4] = (valid[r] != 0u) ? top_score[r] : 0.0f;
        } else {
            out[r * 5 + 0] = 0.0f;
            out[r * 5 + 1] = 0.0f;
            out[r * 5 + 2] = 0.0f;
            out[r * 5 + 3] = 0.0f;
            out[r * 5 + 4] = 0.0f;
        }
    }
}

// ---------------------------------------------------------------- host
extern "C" void kernel_launch(void* const* d_in, const int* in_sizes, int n_in,
                              void* d_out, int out_size, void* d_ws, size_t ws_size,
                              hipStream_t stream) {
    const float* features = (const float*)d_in[0];
    const float* rpn_obj  = (const float*)d_in[1];
    const float* rpn_reg  = (const float*)d_in[2];
    const float* anchors  = (const float*)d_in[3];
    const float* W1 = (const float*)d_in[4];
    const float* b1 = (const float*)d_in[5];
    const float* W2 = (const float*)d_in[6];
    const float* b2 = (const float*)d_in[7];
    const float* W3 = (const float*)d_in[8];
    const float* b3 = (const float*)d_in[9];
    float* out = (float*)d_out;

    char* ws = (char*)d_ws;
    size_t off = 0;
    auto alloc = [&](size_t bytes) {
        char* p = ws + off;
        off += (bytes + 255) & ~(size_t)255;
        return p;
    };
    float*    scores    = (float*)alloc(NA * sizeof(float));
    float*    boxes     = (float*)alloc(NA * 4 * sizeof(float));
    unsigned* hist      = (unsigned*)alloc(NB * sizeof(unsigned));
    unsigned* thr       = (unsigned*)alloc(sizeof(unsigned));
    unsigned* cnt       = (unsigned*)alloc(sizeof(unsigned));
    unsigned long long* cand = (unsigned long long*)alloc(CMAX * 8);
    unsigned* top_idx   = (unsigned*)alloc(MAXD * sizeof(unsigned));
    float*    top_score = (float*)alloc(MAXD * sizeof(float));
    unsigned* valid     = (unsigned*)alloc(MAXD * sizeof(unsigned));
    float*    sel       = (float*)alloc(MAXD * 4 * sizeof(float));
    unsigned long long* mask = (unsigned long long*)alloc(MAXD * 8 * 8);
    unsigned* keep      = (unsigned*)alloc(MAXD * sizeof(unsigned));
    unsigned short* pooled = (unsigned short*)alloc((size_t)MAXD * FIN * 2);
    unsigned short* W1t = (unsigned short*)alloc((size_t)FIN * HID * 2);
    unsigned short* W2t = (unsigned short*)alloc((size_t)HID * HID * 2);
    unsigned short* h1  = (unsigned short*)alloc((size_t)MAXD * HID * 2);
    float*    h2        = (float*)alloc((size_t)MAXD * HID * sizeof(float));
    float*    Cpart     = (float*)alloc((size_t)SPLITK * MAXD * HID * sizeof(float));
    (void)ws_size; (void)in_sizes; (void)n_in; (void)out_size;

    init_kernel<<<(NB + 255) / 256, 256, 0, stream>>>(hist, cnt);
    score_box_kernel<<<NA / 256, 256, 0, stream>>>(rpn_obj, rpn_reg, anchors,
                                                   scores, boxes, hist);
    bucket_threshold_kernel<<<1, 1024, 0, stream>>>(hist, thr);
    compact_kernel<<<NA / 256, 256, 0, stream>>>(scores, thr, cnt, cand);
    sort_topk_kernel<<<1, 1024, 0, stream>>>(cand, cnt, boxes,
                                             top_idx, top_score, valid, sel);
    iou_mask_kernel<<<MAXD, 512, 0, stream>>>(sel, mask);
    nms_scan_kernel<<<1, 64, 0, stream>>>(mask, valid, keep);
    roialign_kernel<<<MAXD, 256, 0, stream>>>(features, sel, pooled);

    // weight transpose+convert (runs each launch; independent of RPN chain)
    transpose_bf16_kernel<<<dim3(HID / 32, FIN / 32), 256, 0, stream>>>(W1, W1t, FIN, HID);
    transpose_bf16_kernel<<<dim3(HID / 32, HID / 32), 256, 0, stream>>>(W2, W2t, HID, HID);

    const int MN = MAXD * HID;
    // GEMM1: pooled(512x4608) @ W1 -> h1 (bf16)
    mfma_gemm_kernel<<<dim3(HID / 64, MAXD / 64, SPLITK), 256, 0, stream>>>(
        pooled, W1t, Cpart, MAXD, HID, FIN);
    reduce_bias_relu_kernel<<<MN / 4 / 256, 256, 0, stream>>>(
        Cpart, b1, h1, (float*)nullptr, MN, HID);
    // GEMM2: h1(512x1024) @ W2 -> h2 (fp32)
    mfma_gemm_kernel<<<dim3(HID / 64, MAXD / 64, SPLITK), 256, 0, stream>>>(
        h1, W2t, Cpart, MAXD, HID, HID);
    reduce_bias_relu_kernel<<<MN / 4 / 256, 256, 0, stream>>>(
        Cpart, b2, (unsigned short*)nullptr, h2, MN, HID);

    head_kernel<<<MAXD, 64, 0, stream>>>(h2, W3, b3, sel, top_score, valid,
                                         keep, out);
}

// Round 3
// 230.046 us; speedup vs baseline: 2.3023x; 1.1969x over previous
//
#include <hip/hip_runtime.h>
#include <math.h>

#define HFD 128
#define WFD 128
#define DFD 512
#define KA  4
#define NA  (HFD*WFD*KA)      // 65536
#define MAXD 512
#define HID 1024
#define FIN 4608              // 3*3*512
#define NB  1025
#define CMAX 2048
#define TAUF 0.5f
#define NMS_THR 0.3f
#define SPLITK 8

typedef __bf16 bf16x8 __attribute__((ext_vector_type(8)));
typedef float  floatx4 __attribute__((ext_vector_type(4)));

__device__ __forceinline__ unsigned short f2bf(float x) {
    unsigned u = __float_as_uint(x);
    unsigned r = (u + 0x7FFFu + ((u >> 16) & 1u)) >> 16;   // RNE
    return (unsigned short)r;
}

// ---------------------------------------------------------------- init
__global__ void init_kernel(unsigned* hist, unsigned* cnt) {
    int t = blockIdx.x * blockDim.x + threadIdx.x;
    if (t < NB) hist[t] = 0u;
    if (t == 0) cnt[0] = 0u;
}

// ------------------------------------------------- score + box decode
__global__ void score_box_kernel(const float* __restrict__ rpn_obj,
                                 const float* __restrict__ rpn_reg,
                                 const float* __restrict__ anchors,
                                 float* __restrict__ scores,
                                 float* __restrict__ boxes,
                                 unsigned* __restrict__ hist) {
    int n = blockIdx.x * blockDim.x + threadIdx.x;
    if (n >= NA) return;
    int k = n & 3;
    int cell = n >> 2;
    float o0 = rpn_obj[cell * 8 + 2 * k];
    float o1 = rpn_obj[cell * 8 + 2 * k + 1];
    float m  = fmaxf(o0, o1);
    float e0 = expf(o0 - m), e1 = expf(o1 - m);
    float s  = e1 / (e0 + e1);

    float r0 = rpn_reg[cell * 16 + 4 * k + 0];
    float r1 = rpn_reg[cell * 16 + 4 * k + 1];
    float r2 = rpn_reg[cell * 16 + 4 * k + 2];
    float r3 = rpn_reg[cell * 16 + 4 * k + 3];

    float ax = anchors[n * 4 + 0];
    float ay = anchors[n * 4 + 1];
    float aw = anchors[n * 4 + 2];
    float ah = anchors[n * 4 + 3];

    float acx = ax + aw * 0.5f;
    float acy = ay + ah * 0.5f;
    float cx = acx + r0 * aw;
    float cy = acy + r1 * ah;
    float w  = aw * expf(r2);
    float h  = ah * expf(r3);

    boxes[n * 4 + 0] = cx - 0.5f * w;
    boxes[n * 4 + 1] = cy - 0.5f * h;
    boxes[n * 4 + 2] = w;
    boxes[n * 4 + 3] = h;

    scores[n] = (s > TAUF) ? s : -INFINITY;
    if (s > TAUF) {
        unsigned bits = __float_as_uint(s);
        unsigned b = (bits - 0x3F000000u) >> 13;   // 0..1024
        atomicAdd(&hist[b], 1u);
    }
}

// ------------------------------------------- find threshold bucket
__global__ void bucket_threshold_kernel(const unsigned* __restrict__ hist,
                                        unsigned* __restrict__ thr) {
    __shared__ unsigned h[NB];
    for (int i = threadIdx.x; i < NB; i += blockDim.x) h[i] = hist[i];
    __syncthreads();
    if (threadIdx.x == 0) {
        unsigned acc = 0;
        int b = NB - 1;
        for (; b >= 0; --b) {
            acc += h[b];
            if (acc >= MAXD) break;
        }
        if (b < 0) b = 0;
        thr[0] = (unsigned)b;
    }
}

// ------------------------------------------------------- compaction
__global__ void compact_kernel(const float* __restrict__ scores,
                               const unsigned* __restrict__ thr,
                               unsigned* __restrict__ cnt,
                               unsigned long long* __restrict__ cand) {
    int n = blockIdx.x * blockDim.x + threadIdx.x;
    if (n >= NA) return;
    float s = scores[n];
    if (s > TAUF) {
        unsigned bits = __float_as_uint(s);
        unsigned b = (bits - 0x3F000000u) >> 13;
        if (b >= thr[0]) {
            unsigned pos = atomicAdd(cnt, 1u);
            if (pos < CMAX) {
                cand[pos] = ((unsigned long long)bits << 32) |
                            (unsigned long long)(~(unsigned)n);
            }
        }
    }
}

// --------------------------------- single-block bitonic sort + top-512
__global__ __launch_bounds__(1024)
void sort_topk_kernel(const unsigned long long* __restrict__ cand,
                      const unsigned* __restrict__ cnt_p,
                      const float* __restrict__ boxes,
                      unsigned* __restrict__ top_idx,
                      float* __restrict__ top_score,
                      unsigned* __restrict__ valid,
                      float* __restrict__ sel) {
    __shared__ unsigned long long keys[CMAX];
    unsigned cnt = *cnt_p;
    if (cnt > CMAX) cnt = CMAX;
    for (int i = threadIdx.x; i < CMAX; i += blockDim.x)
        keys[i] = (i < (int)cnt) ? cand[i] : 0ULL;
    __syncthreads();

    for (int k = 2; k <= CMAX; k <<= 1) {
        for (int j = k >> 1; j > 0; j >>= 1) {
            for (int i = threadIdx.x; i < CMAX; i += blockDim.x) {
                int ixj = i ^ j;
                if (ixj > i) {
                    unsigned long long a = keys[i], b = keys[ixj];
                    bool up = ((i & k) == 0);       // descending overall
                    if ((a < b) == up) { keys[i] = b; keys[ixj] = a; }
                }
            }
            __syncthreads();
        }
    }

    for (int r = threadIdx.x; r < MAXD; r += blockDim.x) {
        unsigned long long e = keys[r];
        unsigned sbits = (unsigned)(e >> 32);
        bool v = (sbits != 0u);
        unsigned idx = v ? (unsigned)(~(unsigned)e) : 0u;
        top_idx[r]   = idx;
        top_score[r] = v ? __uint_as_float(sbits) : 0.0f;
        valid[r]     = v ? 1u : 0u;
        float4 b = *(const float4*)&boxes[idx * 4];
        ((float4*)sel)[r] = b;
    }
}

// ---------------------------------------------------- IoU bitmask
__global__ __launch_bounds__(512)
void iou_mask_kernel(const float* __restrict__ sel,
                     unsigned long long* __restrict__ mask) {
    int i = blockIdx.x;
    int j = threadIdx.x;
    float4 bi = ((const float4*)sel)[i];
    float4 bj = ((const float4*)sel)[j];
    float x2i = bi.x + bi.z, y2i = bi.y + bi.w;
    float x2j = bj.x + bj.z, y2j = bj.y + bj.w;
    float ai = bi.z * bi.w, aj = bj.z * bj.w;
    float ix = fmaxf(0.0f, fminf(x2i, x2j) - fmaxf(bi.x, bj.x));
    float iy = fmaxf(0.0f, fminf(y2i, y2j) - fmaxf(bi.y, bj.y));
    float inter = ix * iy;
    float iou = inter / (ai + aj - inter + 1e-8f);
    unsigned long long bal = __ballot(iou > NMS_THR);
    if ((j & 63) == 0) mask[i * 8 + (j >> 6)] = bal;
}

// ------------------- sequential NMS, ballot-pipelined (1 wave, ~3 µs)
// Groups of 64 rows. Cross-group suppression is parallel VALU; the
// intra-group 64-step serial resolve uses ballots that do NOT depend on
// the serial state, so only a 3-op scalar chain per step is serial.
__global__ __launch_bounds__(64)
void nms_scan_kernel(const unsigned long long* __restrict__ mask,
                     const unsigned* __restrict__ valid,
                     unsigned* __restrict__ keep) {
    int lane = threadIdx.x;
    unsigned long long w[8][8];   // [g][t<=g] : mask word t of row 64g+lane
#pragma unroll
    for (int g = 0; g < 8; ++g)
#pragma unroll
        for (int t = 0; t < 8; ++t)
            if (t <= g) w[g][t] = mask[(g * 64 + lane) * 8 + t];
    unsigned long long vb[8];
#pragma unroll
    for (int g = 0; g < 8; ++g)
        vb[g] = __ballot(valid[g * 64 + lane] != 0u);

    unsigned long long keepw[8];
#pragma unroll
    for (int g = 0; g < 8; ++g) {
        bool pre = false;
#pragma unroll
        for (int t = 0; t < 8; ++t)
            if (t < g) pre = pre || ((w[g][t] & keepw[t]) != 0ULL);
        unsigned long long alive = vb[g] & ~__ballot(pre);
        unsigned long long intra = w[g][g];
        unsigned long long kg = 0ULL;
#pragma unroll
        for (int b = 0; b < 64; ++b) {
            // suppression column for box b — independent of serial state
            unsigned long long sup = __ballot((intra >> b) & 1ULL);
            if ((alive >> b) & 1ULL) {     // wave-uniform branch
                kg |= 1ULL << b;
                alive &= ~sup;
            }
        }
        keepw[g] = kg;
    }
#pragma unroll
    for (int g = 0; g < 8; ++g)
        keep[g * 64 + lane] = (unsigned)((keepw[g] >> lane) & 1ULL);
}

// ------------------------------------------- ROI align (bf16 output)
__global__ __launch_bounds__(256)
void roialign_kernel(const float* __restrict__ feat,
                     const float* __restrict__ sel,
                     unsigned short* __restrict__ pooled) {
    int mrow = blockIdx.x;
    int c = threadIdx.x;           // channels c and c+256
    float4 b = ((const float4*)sel)[mrow];
    float bx = b.x, by = b.y, bw = b.z, bh = b.w;
    float vmax0[9], vmax1[9];
#pragma unroll
    for (int t = 0; t < 9; ++t) { vmax0[t] = -INFINITY; vmax1[t] = -INFINITY; }
#pragma unroll
    for (int p = 0; p < 6; ++p) {
        float fy = (by + ((float)p + 0.5f) / 6.0f * bh) / 16.0f - 0.5f;
        fy = fminf(fmaxf(fy, 0.0f), 127.0f);
        int y0 = (int)floorf(fy);
        int y1 = min(y0 + 1, 127);
        float wy = fy - (float)y0;
#pragma unroll
        for (int q = 0; q < 6; ++q) {
            float fx = (bx + ((float)q + 0.5f) / 6.0f * bw) / 16.0f - 0.5f;
            fx = fminf(fmaxf(fx, 0.0f), 127.0f);
            int x0 = (int)floorf(fx);
            int x1 = min(x0 + 1, 127);
            float wx = fx - (float)x0;
            const float* f00 = feat + (y0 * WFD + x0) * DFD;
            const float* f01 = feat + (y0 * WFD + x1) * DFD;
            const float* f10 = feat + (y1 * WFD + x0) * DFD;
            const float* f11 = feat + (y1 * WFD + x1) * DFD;
            float w00 = (1.0f - wy) * (1.0f - wx);
            float w01 = (1.0f - wy) * wx;
            float w10 = wy * (1.0f - wx);
            float w11 = wy * wx;
            int t = (p >> 1) * 3 + (q >> 1);
            float v0 = f00[c] * w00 + f01[c] * w01 + f10[c] * w10 + f11[c] * w11;
            float v1 = f00[c + 256] * w00 + f01[c + 256] * w01 +
                       f10[c + 256] * w10 + f11[c + 256] * w11;
            vmax0[t] = fmaxf(vmax0[t], v0);
            vmax1[t] = fmaxf(vmax1[t], v1);
        }
    }
#pragma unroll
    for (int t = 0; t < 9; ++t) {
        pooled[mrow * FIN + t * DFD + c] = f2bf(vmax0[t]);
        pooled[mrow * FIN + t * DFD + c + 256] = f2bf(vmax1[t]);
    }
}

// ----------------------------- fp32 W[K][N] -> bf16 Wt[N][K] transpose
__global__ __launch_bounds__(256)
void transpose_bf16_kernel(const float* __restrict__ W,
                           unsigned short* __restrict__ Wt,
                           int K, int N) {
    __shared__ float tile[32][33];
    int bk = blockIdx.y * 32;
    int bn = blockIdx.x * 32;
    int tx = threadIdx.x & 31, ty = threadIdx.x >> 5;   // ty 0..7
#pragma unroll
    for (int r = 0; r < 32; r += 8)
        tile[ty + r][tx] = W[(long)(bk + ty + r) * N + bn + tx];
    __syncthreads();
#pragma unroll
    for (int r = 0; r < 32; r += 8)
        Wt[(long)(bn + ty + r) * K + bk + tx] = f2bf(tile[tx][ty + r]);
}

// --------------------------------------- bf16 MFMA GEMM with split-K
// A: M x K bf16 row-major; Bt: N x K bf16 row-major (B transposed)
// Cpart[z][M][N] fp32 partials. grid = (N/64, M/64, SPLITK), 256 thr.
#define LDSTRIDE 40
__global__ __launch_bounds__(256)
void mfma_gemm_kernel(const unsigned short* __restrict__ A,
                      const unsigned short* __restrict__ Bt,
                      float* __restrict__ Cpart,
                      int M, int N, int K) {
    __shared__ unsigned short As[64 * LDSTRIDE];
    __shared__ unsigned short Bs[64 * LDSTRIDE];
    int tid = threadIdx.x;
    int wave = tid >> 6, lane = tid & 63;
    int bm = blockIdx.y * 64, bn = blockIdx.x * 64;
    int KC = K / SPLITK;
    int ks = blockIdx.z * KC;

    floatx4 acc[4] = {};
    int lr = tid >> 2;            // 0..63  staging row
    int lk = (tid & 3) << 3;      // 0,8,16,24  staging k-offset
    int frow = lane & 15, quad = lane >> 4;

    const unsigned short* Ap = A + (long)(bm + lr) * K + lk;
    const unsigned short* Bp = Bt + (long)(bn + lr) * K + lk;

    for (int k0 = ks; k0 < ks + KC; k0 += 32) {
        uint4 av = *(const uint4*)(Ap + k0);
        uint4 bv = *(const uint4*)(Bp + k0);
        *(uint4*)&As[lr * LDSTRIDE + lk] = av;
        *(uint4*)&Bs[lr * LDSTRIDE + lk] = bv;
        __syncthreads();
        bf16x8 af = *(const bf16x8*)&As[(wave * 16 + frow) * LDSTRIDE + quad * 8];
#pragma unroll
        for (int t = 0; t < 4; ++t) {
            bf16x8 bfv = *(const bf16x8*)&Bs[(t * 16 + frow) * LDSTRIDE + quad * 8];
            acc[t] = __builtin_amdgcn_mfma_f32_16x16x32_bf16(af, bfv, acc[t], 0, 0, 0);
        }
        __syncthreads();
    }

    float* Cp = Cpart + (long)blockIdx.z * M * N;
#pragma unroll
    for (int t = 0; t < 4; ++t) {
#pragma unroll
        for (int r = 0; r < 4; ++r) {
            int m = bm + wave * 16 + quad * 4 + r;   // C row = quad*4+reg
            int n = bn + t * 16 + frow;              // C col = lane&15
            Cp[(long)m * N + n] = acc[t][r];
        }
    }
}

// --------------------- split-K reduce + bias + relu, bf16/fp32 output
__global__ __launch_bounds__(256)
void reduce_bias_relu_kernel(const float* __restrict__ Cpart,
                             const float* __restrict__ bias,
                             unsigned short* __restrict__ out_bf,
                             float* __restrict__ out_f,
                             int MN, int N) {
    int i4 = (blockIdx.x * blockDim.x + threadIdx.x) * 4;
    if (i4 >= MN) return;
    float4 s = *(const float4*)&Cpart[i4];
#pragma unroll
    for (int z = 1; z < SPLITK; ++z) {
        float4 p = *(const float4*)&Cpart[(long)z * MN + i4];
        s.x += p.x; s.y += p.y; s.z += p.z; s.w += p.w;
    }
    int n = i4 & (N - 1);
    float4 bi = *(const float4*)&bias[n];
    s.x = fmaxf(s.x + bi.x, 0.0f);
    s.y = fmaxf(s.y + bi.y, 0.0f);
    s.z = fmaxf(s.z + bi.z, 0.0f);
    s.w = fmaxf(s.w + bi.w, 0.0f);
    if (out_bf) {
        uint2 o;
        o.x = (unsigned)f2bf(s.x) | ((unsigned)f2bf(s.y) << 16);
        o.y = (unsigned)f2bf(s.z) | ((unsigned)f2bf(s.w) << 16);
        *(uint2*)&out_bf[i4] = o;
    }
    if (out_f) *(float4*)&out_f[i4] = s;
}

// ------------------------------ final tiny GEMM (N=4) + refine epilogue
__global__ __launch_bounds__(64)
void head_kernel(const float* __restrict__ h2,
                 const float* __restrict__ W3,
                 const float* __restrict__ b3,
                 const float* __restrict__ sel,
                 const float* __restrict__ top_score,
                 const unsigned* __restrict__ valid,
                 const unsigned* __restrict__ keep,
                 float* __restrict__ out) {
    int r = blockIdx.x;
    int lane = threadIdx.x;
    float a0 = 0.f, a1 = 0.f, a2 = 0.f, a3 = 0.f;
    for (int k = lane; k < HID; k += 64) {
        float hv = h2[r * HID + k];
        float4 w = *(const float4*)&W3[k * 4];
        a0 += hv * w.x;
        a1 += hv * w.y;
        a2 += hv * w.z;
        a3 += hv * w.w;
    }
#pragma unroll
    for (int off = 32; off > 0; off >>= 1) {
        a0 += __shfl_down(a0, off);
        a1 += __shfl_down(a1, off);
        a2 += __shfl_down(a2, off);
        a3 += __shfl_down(a3, off);
    }
    if (lane == 0) {
        if (keep[r] != 0u) {
            float d0 = a0 + b3[0], d1 = a1 + b3[1];
            float d2 = a2 + b3[2], d3 = a3 + b3[3];
            float4 b = ((const float4*)sel)[r];
            float acx = b.x + 0.5f * b.z;
            float acy = b.y + 0.5f * b.w;
            float cx = acx + d0 * b.z;
            float cy = acy + d1 * b.w;
            float nw = b.z * expf(d2);
            float nh = b.w * expf(d3);
            out[r * 5 + 0] = cx - 0.5f * nw;
            out[r * 5 + 1] = cy - 0.5f * nh;
            out[r * 5 + 2] = nw;
            out[r * 5 + 3] = nh;
            out[r * 5 + 4] = (valid[r] != 0u) ? top_score[r] : 0.0f;
        } else {
            out[r * 5 + 0] = 0.0f;
            out[r * 5 + 1] = 0.0f;
            out[r * 5 + 2] = 0.0f;
            out[r * 5 + 3] = 0.0f;
            out[r * 5 + 4] = 0.0f;
        }
    }
}

// ---------------------------------------------------------------- host
extern "C" void kernel_launch(void* const* d_in, const int* in_sizes, int n_in,
                              void* d_out, int out_size, void* d_ws, size_t ws_size,
                              hipStream_t stream) {
    const float* features = (const float*)d_in[0];
    const float* rpn_obj  = (const float*)d_in[1];
    const float* rpn_reg  = (const float*)d_in[2];
    const float* anchors  = (const float*)d_in[3];
    const float* W1 = (const float*)d_in[4];
    const float* b1 = (const float*)d_in[5];
    const float* W2 = (const float*)d_in[6];
    const float* b2 = (const float*)d_in[7];
    const float* W3 = (const float*)d_in[8];
    const float* b3 = (const float*)d_in[9];
    float* out = (float*)d_out;

    char* ws = (char*)d_ws;
    size_t off = 0;
    auto alloc = [&](size_t bytes) {
        char* p = ws + off;
        off += (bytes + 255) & ~(size_t)255;
        return p;
    };
    float*    scores    = (float*)alloc(NA * sizeof(float));
    float*    boxes     = (float*)alloc(NA * 4 * sizeof(float));
    unsigned* hist      = (unsigned*)alloc(NB * sizeof(unsigned));
    unsigned* thr       = (unsigned*)alloc(sizeof(unsigned));
    unsigned* cnt       = (unsigned*)alloc(sizeof(unsigned));
    unsigned long long* cand = (unsigned long long*)alloc(CMAX * 8);
    unsigned* top_idx   = (unsigned*)alloc(MAXD * sizeof(unsigned));
    float*    top_score = (float*)alloc(MAXD * sizeof(float));
    unsigned* valid     = (unsigned*)alloc(MAXD * sizeof(unsigned));
    float*    sel       = (float*)alloc(MAXD * 4 * sizeof(float));
    unsigned long long* mask = (unsigned long long*)alloc(MAXD * 8 * 8);
    unsigned* keep      = (unsigned*)alloc(MAXD * sizeof(unsigned));
    unsigned short* pooled = (unsigned short*)alloc((size_t)MAXD * FIN * 2);
    unsigned short* W1t = (unsigned short*)alloc((size_t)FIN * HID * 2);
    unsigned short* W2t = (unsigned short*)alloc((size_t)HID * HID * 2);
    unsigned short* h1  = (unsigned short*)alloc((size_t)MAXD * HID * 2);
    float*    h2        = (float*)alloc((size_t)MAXD * HID * sizeof(float));
    float*    Cpart     = (float*)alloc((size_t)SPLITK * MAXD * HID * sizeof(float));
    (void)ws_size; (void)in_sizes; (void)n_in; (void)out_size;

    init_kernel<<<(NB + 255) / 256, 256, 0, stream>>>(hist, cnt);
    score_box_kernel<<<NA / 256, 256, 0, stream>>>(rpn_obj, rpn_reg, anchors,
                                                   scores, boxes, hist);
    bucket_threshold_kernel<<<1, 1024, 0, stream>>>(hist, thr);
    compact_kernel<<<NA / 256, 256, 0, stream>>>(scores, thr, cnt, cand);
    sort_topk_kernel<<<1, 1024, 0, stream>>>(cand, cnt, boxes,
                                             top_idx, top_score, valid, sel);
    iou_mask_kernel<<<MAXD, 512, 0, stream>>>(sel, mask);
    nms_scan_kernel<<<1, 64, 0, stream>>>(mask, valid, keep);
    roialign_kernel<<<MAXD, 256, 0, stream>>>(features, sel, pooled);

    // weight transpose+convert (runs each launch; independent of RPN chain)
    transpose_bf16_kernel<<<dim3(HID / 32, FIN / 32), 256, 0, stream>>>(W1, W1t, FIN, HID);
    transpose_bf16_kernel<<<dim3(HID / 32, HID / 32), 256, 0, stream>>>(W2, W2t, HID, HID);

    const int MN = MAXD * HID;
    // GEMM1: pooled(512x4608) @ W1 -> h1 (bf16)
    mfma_gemm_kernel<<<dim3(HID / 64, MAXD / 64, SPLITK), 256, 0, stream>>>(
        pooled, W1t, Cpart, MAXD, HID, FIN);
    reduce_bias_relu_kernel<<<MN / 4 / 256, 256, 0, stream>>>(
        Cpart, b1, h1, (float*)nullptr, MN, HID);
    // GEMM2: h1(512x1024) @ W2 -> h2 (fp32)
    mfma_gemm_kernel<<<dim3(HID / 64, MAXD / 64, SPLITK), 256, 0, stream>>>(
        h1, W2t, Cpart, MAXD, HID, HID);
    reduce_bias_relu_kernel<<<MN / 4 / 256, 256, 0, stream>>>(
        Cpart, b2, (unsigned short*)nullptr, h2, MN, HID);

    head_kernel<<<MAXD, 64, 0, stream>>>(h2, W3, b3, sel, top_score, valid,
                                         keep, out);
}